// Round 6
// baseline (1777.492 us; speedup 1.0000x reference)
//
#include <hip/hip_runtime.h>
#include <hip/hip_bf16.h>
#include <stdint.h>

// Problem constants
// B=4 N=4 -> 16 batch instances; CX=512 CF=256 HID=256 OUT=512 H=W=48 -> P=2304
#define PPIX 2304L
#define FEATC 1536

typedef __attribute__((ext_vector_type(8))) short short8;
typedef __attribute__((ext_vector_type(4))) short short4v;
typedef __attribute__((ext_vector_type(4))) float f32x4;

__device__ __forceinline__ short f2bf(float f) {
  union { float f; uint32_t u; } v; v.f = f;
  return (short)((v.u + 0x7fffu + ((v.u >> 16) & 1u)) >> 16);
}

// async global->LDS, 16B per lane; lds dest = wave-uniform base + lane*16B
__device__ __forceinline__ void gld16(const void* g, void* l) {
  __builtin_amdgcn_global_load_lds(
      (const __attribute__((address_space(1))) void*)g,
      (__attribute__((address_space(3))) void*)l, 16, 0, 0);
}

// ---------------- elementwise f32 -> bf16 (vectorized x4) ----------------
__global__ void k_conv_bf16(const float* __restrict__ src, short* __restrict__ dst, long n4) {
  long i = (long)blockIdx.x * blockDim.x + threadIdx.x;
  long stride = (long)gridDim.x * blockDim.x;
  for (long j = i; j < n4; j += stride) {
    float4 v = ((const float4*)src)[j];
    short4v o;
    o[0] = f2bf(v.x); o[1] = f2bf(v.y); o[2] = f2bf(v.z); o[3] = f2bf(v.w);
    ((short4v*)dst)[j] = o;
  }
}

// ---------------- tiled transpose f32 [R][C] -> bf16 [C][R] (ldDst), rep dst slots ----------------
__global__ __launch_bounds__(256) void k_transpose_bf16(
    const float* __restrict__ src, long srcZ,
    short* __restrict__ dst, long dstZ,
    int srcCols, int ldDst, int rep) {
  __shared__ float tile[32][33];
  const int z = blockIdx.z;
  const float* s = src + (long)z * srcZ;
  const int c0 = blockIdx.x * 32, r0 = blockIdx.y * 32;
  #pragma unroll
  for (int j = 0; j < 4; j++)
    tile[threadIdx.y + j * 8][threadIdx.x] =
        s[(long)(r0 + threadIdx.y + j * 8) * srcCols + c0 + threadIdx.x];
  __syncthreads();
  short vals[4];
  #pragma unroll
  for (int j = 0; j < 4; j++) vals[j] = f2bf(tile[threadIdx.x][threadIdx.y + j * 8]);
  for (int rr = 0; rr < rep; rr++) {
    short* d = dst + (long)(z * rep + rr) * dstZ;
    #pragma unroll
    for (int j = 0; j < 4; j++)
      d[(long)(c0 + threadIdx.y + j * 8) * ldDst + r0 + threadIdx.x] = vals[j];
  }
}

// ---------------- row softmax: S f32 [z][2304][2304] -> P bf16, float4 vectorized ----------------
__global__ __launch_bounds__(192) void k_softmax(const float* __restrict__ S, short* __restrict__ P) {
  __shared__ float red[6];
  const long base = ((long)blockIdx.y * 2304 + blockIdx.x) * 2304;
  const float4* s4 = (const float4*)(S + base);
  short4v* p4 = (short4v*)(P + base);
  const int t = threadIdx.x;
  const int lane = t & 63, wave = t >> 6;
  float4 v[3];
  float mx = -3.4e38f;
  #pragma unroll
  for (int j = 0; j < 3; j++) {
    v[j] = s4[t + j * 192];
    mx = fmaxf(mx, fmaxf(fmaxf(v[j].x, v[j].y), fmaxf(v[j].z, v[j].w)));
  }
  #pragma unroll
  for (int o = 32; o >= 1; o >>= 1) mx = fmaxf(mx, __shfl_xor(mx, o));
  if (lane == 0) red[wave] = mx;
  __syncthreads();
  mx = fmaxf(fmaxf(red[0], red[1]), red[2]);
  float sum = 0.f;
  #pragma unroll
  for (int j = 0; j < 3; j++) {
    v[j].x = __expf(v[j].x - mx); v[j].y = __expf(v[j].y - mx);
    v[j].z = __expf(v[j].z - mx); v[j].w = __expf(v[j].w - mx);
    sum += v[j].x + v[j].y + v[j].z + v[j].w;
  }
  #pragma unroll
  for (int o = 32; o >= 1; o >>= 1) sum += __shfl_xor(sum, o);
  if (lane == 0) red[3 + wave] = sum;
  __syncthreads();
  float inv = 1.f / (red[3] + red[4] + red[5]);
  #pragma unroll
  for (int j = 0; j < 3; j++) {
    short4v o;
    o[0] = f2bf(v[j].x * inv); o[1] = f2bf(v[j].y * inv);
    o[2] = f2bf(v[j].z * inv); o[3] = f2bf(v[j].w * inv);
    p4[t + j * 192] = o;
  }
}

// ---------------- generic bf16 MFMA GEMM: C[m][n] = sum_k A[m][k]*Bt[n][k] (+bias) ----------------
// 128x128 tile, BK=32, 4 waves (2x2), 4x4 16x16x32 frags/wave, global_load_lds staging (m97).
// Per-operand batch offset: ptr + ((i0+z)/div)*str
template<int BIAS_MODE, int OUT_F32>   // BIAS_MODE: 0 none, 1 per-row(m), 2 per-col(n)
__global__ __launch_bounds__(256) void k_gemm_bt(
    const short* __restrict__ Ab, long aStr, int aDiv, int aI0, int lda,
    const short* __restrict__ Bb, long bStr, int bDiv, int bI0, int ldb,
    void* __restrict__ Cb, long cStr, int cDiv, int cI0, int ldc,
    const float* __restrict__ bias, int K) {
  __shared__ short As[128 * 32];
  __shared__ short Bs[128 * 32];
  const int z = blockIdx.z;
  const short* A = Ab + (long)((aI0 + z) / aDiv) * aStr;
  const short* B = Bb + (long)((bI0 + z) / bDiv) * bStr;
  const int m0 = blockIdx.y * 128, n0 = blockIdx.x * 128;
  const int t = threadIdx.x;
  const int lane = t & 63, wave = t >> 6;
  const int wr = wave >> 1, wc = wave & 1;

  // staging map: thread t covers rows (t>>2) and 64+(t>>2), k-chunk (t&3)*8 (16B)
  // => LDS byte offset t*16 (linear in thread order): global_load_lds compatible.
  const int sr = t >> 2;
  const int sc = (t & 3) * 8;
  const short* Ag0 = A + (long)(m0 + sr) * lda + sc;
  const short* Ag1 = A + (long)(m0 + 64 + sr) * lda + sc;
  const short* Bg0 = B + (long)(n0 + sr) * ldb + sc;
  const short* Bg1 = B + (long)(n0 + 64 + sr) * ldb + sc;
  // wave-uniform LDS bases (HW writes lane l at base + l*16B)
  short* lA0 = As + wave * 512;
  short* lA1 = As + 2048 + wave * 512;
  short* lB0 = Bs + wave * 512;
  short* lB1 = Bs + 2048 + wave * 512;

  f32x4 acc[4][4];
  #pragma unroll
  for (int i = 0; i < 4; i++)
    #pragma unroll
    for (int j = 0; j < 4; j++)
      acc[i][j] = (f32x4){0.f, 0.f, 0.f, 0.f};

  const int fr = lane & 15;        // frag row within 16 (m or n)
  const int fk = (lane >> 4) * 8;  // frag k offset (8 contiguous bf16)

  for (int k0 = 0; k0 < K; k0 += 32) {
    __syncthreads();               // previous compute done before overwrite
    gld16(Ag0 + k0, lA0);
    gld16(Ag1 + k0, lA1);
    gld16(Bg0 + k0, lB0);
    gld16(Bg1 + k0, lB1);
    __syncthreads();               // vmcnt drained by compiler before barrier
    short8 af[4], bfr[4];
    #pragma unroll
    for (int mf = 0; mf < 4; mf++)
      af[mf] = *(const short8*)&As[(wr * 64 + mf * 16 + fr) * 32 + fk];
    #pragma unroll
    for (int nf = 0; nf < 4; nf++)
      bfr[nf] = *(const short8*)&Bs[(wc * 64 + nf * 16 + fr) * 32 + fk];
    #pragma unroll
    for (int mf = 0; mf < 4; mf++)
      #pragma unroll
      for (int nf = 0; nf < 4; nf++)
        acc[mf][nf] = __builtin_amdgcn_mfma_f32_16x16x32_bf16(af[mf], bfr[nf], acc[mf][nf], 0, 0, 0);
  }

  // C/D frag layout (m89-verified): col = lane&15, row = (lane>>4)*4 + j
  const int cc = lane & 15;
  const int rg = (lane >> 4) * 4;
  const long coff = (long)((cI0 + z) / cDiv) * cStr;
  #pragma unroll
  for (int mf = 0; mf < 4; mf++) {
    #pragma unroll
    for (int nf = 0; nf < 4; nf++) {
      #pragma unroll
      for (int j = 0; j < 4; j++) {
        int m = m0 + wr * 64 + mf * 16 + rg + j;
        int n = n0 + wc * 64 + nf * 16 + cc;
        float v = acc[mf][nf][j];
        if (BIAS_MODE == 1) v += bias[m];
        if (BIAS_MODE == 2) v += bias[n];
        if (OUT_F32) ((float*)Cb)[coff + (long)m * ldc + n] = v;
        else         ((short*)Cb)[coff + (long)m * ldc + n] = f2bf(v);
      }
    }
  }
}

extern "C" void kernel_launch(void* const* d_in, const int* in_sizes, int n_in,
                              void* d_out, int out_size, void* d_ws, size_t ws_size,
                              hipStream_t stream) {
  const float* mv  = (const float*)d_in[0];   // [16][512][2304]
  const float* ff  = (const float*)d_in[1];   // [4][256][2304]
  const float* wq1 = (const float*)d_in[2];   // [256][512]
  const float* bq1 = (const float*)d_in[3];
  const float* wk1 = (const float*)d_in[4];   // [256][256]
  const float* bk1 = (const float*)d_in[5];
  const float* wq2 = (const float*)d_in[6];   // [256][256]
  const float* bq2 = (const float*)d_in[7];
  const float* wk2 = (const float*)d_in[8];   // [256][512]
  const float* bk2 = (const float*)d_in[9];
  const float* wdr = (const float*)d_in[10];  // [512][1536]
  const float* bdr = (const float*)d_in[11];
  float* out = (float*)d_out;                 // [16][512][2304]

  // ---- carve workspace ----
  unsigned char* w = (unsigned char*)d_ws;
  auto carve = [&](size_t bytes) -> short* {
    short* r = (short*)w;
    w += (bytes + 255) & ~(size_t)255;
    return r;
  };
  const long FEAT_Z = PPIX * FEATC;            // per-i featT elements
  const long QKZ = PPIX * 256;                 // per-slot Q/K elements
  const long SZ = PPIX * PPIX;
  short* featT = carve(16 * FEAT_Z * 2);       // [16][2304][1536] bf16
  short* mv_bf = carve(16L * 512 * PPIX * 2);  // [16][512][2304]
  short* ff_bf = carve(4L * 256 * PPIX * 2);   // [4][256][2304]
  short* q1t   = carve(16 * QKZ * 2);
  short* k2t   = carve(16 * QKZ * 2);
  short* q2t   = carve(4 * QKZ * 2);
  short* k1t   = carve(4 * QKZ * 2);
  short* wq1b  = carve(256L * 512 * 2);
  short* wk1b  = carve(256L * 256 * 2);
  short* wq2b  = carve(256L * 256 * 2);
  short* wk2b  = carve(256L * 512 * 2);
  short* wdrb  = carve(512L * 1536 * 2);

  size_t used = (size_t)(w - (unsigned char*)d_ws);
  const size_t perz = (size_t)SZ * 4 + (size_t)SZ * 2;  // S f32 + P bf16 per z
  // zb=4 preferred: S+P chunk (~128 MB) stays resident in the 256 MB L3,
  // so S/P round-trips never hit HBM. Larger zb would blow L3.
  int zb = 1;
  {
    const int cands[3] = {4, 2, 1};
    for (int c = 0; c < 3; c++) {
      if (used + (size_t)cands[c] * perz <= ws_size) { zb = cands[c]; break; }
    }
  }
  float* Sbuf = (float*)carve((size_t)zb * SZ * 4);
  short* Pbuf = carve((size_t)zb * SZ * 2);

  // ---- prep: converts ----
  auto conv = [&](const float* s, short* d, long n) {
    long blocks = (n / 4 + 255) / 256;
    if (blocks > 2048) blocks = 2048;
    k_conv_bf16<<<dim3((int)blocks), dim3(256), 0, stream>>>(s, d, n / 4);
  };
  conv(mv, mv_bf, 16L * 512 * PPIX);
  conv(ff, ff_bf, 4L * 256 * PPIX);
  conv(wq1, wq1b, 256L * 512);
  conv(wk1, wk1b, 256L * 256);
  conv(wq2, wq2b, 256L * 256);
  conv(wk2, wk2b, 256L * 512);
  conv(wdr, wdrb, 512L * 1536);

  // ---- prep: transposes into featT (cols 0-511 = mvT, 1024-1279 = ffT) ----
  k_transpose_bf16<<<dim3(72, 16, 16), dim3(32, 8), 0, stream>>>(
      mv, 512L * PPIX, featT, FEAT_Z, (int)PPIX, FEATC, 1);
  k_transpose_bf16<<<dim3(72, 8, 4), dim3(32, 8), 0, stream>>>(
      ff, 256L * PPIX, featT + 1024, FEAT_Z, (int)PPIX, FEATC, 4);

  // ---- generic GEMM launcher ----
  auto gemm = [&](int biasMode, int outF32,
                  const short* A, long aStr, int aDiv, int aI0, int lda,
                  const short* B, long bStr, int bDiv, int bI0, int ldb,
                  void* C, long cStr, int cDiv, int cI0, int ldc,
                  const float* bias, int M, int N, int K, int Z) {
    dim3 g(N / 128, M / 128, Z), b(256);
    if (biasMode == 2 && !outF32)
      k_gemm_bt<2, 0><<<g, b, 0, stream>>>(A, aStr, aDiv, aI0, lda, B, bStr, bDiv, bI0, ldb,
                                           C, cStr, cDiv, cI0, ldc, bias, K);
    else if (biasMode == 0 && outF32)
      k_gemm_bt<0, 1><<<g, b, 0, stream>>>(A, aStr, aDiv, aI0, lda, B, bStr, bDiv, bI0, ldb,
                                           C, cStr, cDiv, cI0, ldc, bias, K);
    else if (biasMode == 0 && !outF32)
      k_gemm_bt<0, 0><<<g, b, 0, stream>>>(A, aStr, aDiv, aI0, lda, B, bStr, bDiv, bI0, ldb,
                                           C, cStr, cDiv, cI0, ldc, bias, K);
    else
      k_gemm_bt<1, 1><<<g, b, 0, stream>>>(A, aStr, aDiv, aI0, lda, B, bStr, bDiv, bI0, ldb,
                                           C, cStr, cDiv, cI0, ldc, bias, K);
  };

  // ---- projections ----
  gemm(2, 0, featT, FEAT_Z, 1, 0, FEATC,  wq1b, 0, 1, 0, 512,
       q1t, QKZ, 1, 0, 256,  bq1, (int)PPIX, 256, 512, 16);
  gemm(2, 0, featT, FEAT_Z, 1, 0, FEATC,  wk2b, 0, 1, 0, 512,
       k2t, QKZ, 1, 0, 256,  bk2, (int)PPIX, 256, 512, 16);
  gemm(2, 0, featT + 1024, 4 * FEAT_Z, 1, 0, FEATC,  wq2b, 0, 1, 0, 256,
       q2t, QKZ, 1, 0, 256,  bq2, (int)PPIX, 256, 256, 4);
  gemm(2, 0, featT + 1024, 4 * FEAT_Z, 1, 0, FEATC,  wk1b, 0, 1, 0, 256,
       k1t, QKZ, 1, 0, 256,  bk1, (int)PPIX, 256, 256, 4);

  // ---- attention (chunks of zb batches; S/P stay L3-resident) ----
  for (int i0 = 0; i0 < 16; i0 += zb) {
    // layer 1: S = Q1T_i x K1T_b^T ; P = softmax(S) ; O1 = P x ff_b^T -> featT cols 1280-1535
    gemm(0, 1, q1t, QKZ, 1, i0, 256,  k1t, QKZ, 4, i0, 256,
         Sbuf, SZ, 1, 0, (int)PPIX,  nullptr, (int)PPIX, (int)PPIX, 256, zb);
    k_softmax<<<dim3(2304, zb), dim3(192), 0, stream>>>(Sbuf, Pbuf);
    gemm(0, 0, Pbuf, SZ, 1, 0, (int)PPIX,  ff_bf, 256L * PPIX, 4, i0, (int)PPIX,
         featT + 1280, FEAT_Z, 1, i0, FEATC,  nullptr, (int)PPIX, 256, (int)PPIX, zb);
    // layer 2: S = Q2T_b x K2T_i^T ; P = softmax(S) ; O2 = P x mv_i^T -> featT cols 512-1023
    gemm(0, 1, q2t, QKZ, 4, i0, 256,  k2t, QKZ, 1, i0, 256,
         Sbuf, SZ, 1, 0, (int)PPIX,  nullptr, (int)PPIX, (int)PPIX, 256, zb);
    k_softmax<<<dim3(2304, zb), dim3(192), 0, stream>>>(Sbuf, Pbuf);
    gemm(0, 0, Pbuf, SZ, 1, 0, (int)PPIX,  mv_bf, 512L * PPIX, 1, i0, (int)PPIX,
         featT + 512, FEAT_Z, 1, i0, FEATC,  nullptr, (int)PPIX, 512, (int)PPIX, zb);
  }

  // ---- final 1x1 conv: out[i][o][p] = sum_ch wdr[o][ch]*featT[i][p][ch] + bdr[o] ----
  gemm(1, 1, wdrb, 0, 1, 0, FEATC,  featT, FEAT_Z, 1, 0, FEATC,
       out, 512L * PPIX, 1, 0, (int)PPIX,  bdr, 512, (int)PPIX, FEATC, 16);

  (void)in_sizes; (void)n_in; (void)out_size; (void)ws_size;
}

// Round 8
// 1182.919 us; speedup vs baseline: 1.5026x; 1.5026x over previous
//
#include <hip/hip_runtime.h>
#include <hip/hip_bf16.h>
#include <stdint.h>

// B=4 N=4 -> 16 batch instances; CX=512 CF=256 HID=256 OUT=512 H=W=48 -> P=2304
#define PPIX 2304L
#define FEATC 1536

typedef __attribute__((ext_vector_type(8))) short short8;
typedef __attribute__((ext_vector_type(4))) short short4v;
typedef __attribute__((ext_vector_type(4))) float f32x4;

__device__ __forceinline__ short f2bf(float f) {
  union { float f; uint32_t u; } v; v.f = f;
  return (short)((v.u + 0x7fffu + ((v.u >> 16) & 1u)) >> 16);
}

// async global->LDS, 16B per lane; lds dest = wave-uniform base + lane*16B
__device__ __forceinline__ void gld16(const void* g, void* l) {
  __builtin_amdgcn_global_load_lds(
      (const __attribute__((address_space(1))) void*)g,
      (__attribute__((address_space(3))) void*)l, 16, 0, 0);
}

// ---------------- elementwise f32 -> bf16 (vectorized x4) ----------------
__global__ void k_conv_bf16(const float* __restrict__ src, short* __restrict__ dst, long n4) {
  long i = (long)blockIdx.x * blockDim.x + threadIdx.x;
  long stride = (long)gridDim.x * blockDim.x;
  for (long j = i; j < n4; j += stride) {
    float4 v = ((const float4*)src)[j];
    short4v o;
    o[0] = f2bf(v.x); o[1] = f2bf(v.y); o[2] = f2bf(v.z); o[3] = f2bf(v.w);
    ((short4v*)dst)[j] = o;
  }
}

// ---------------- tiled transpose f32 [R][C] -> bf16 [C][R] (ldDst), rep dst slots ----------------
__global__ __launch_bounds__(256) void k_transpose_bf16(
    const float* __restrict__ src, long srcZ,
    short* __restrict__ dst, long dstZ,
    int srcCols, int ldDst, int rep) {
  __shared__ float tile[32][33];
  const int z = blockIdx.z;
  const float* s = src + (long)z * srcZ;
  const int c0 = blockIdx.x * 32, r0 = blockIdx.y * 32;
  #pragma unroll
  for (int j = 0; j < 4; j++)
    tile[threadIdx.y + j * 8][threadIdx.x] =
        s[(long)(r0 + threadIdx.y + j * 8) * srcCols + c0 + threadIdx.x];
  __syncthreads();
  short vals[4];
  #pragma unroll
  for (int j = 0; j < 4; j++) vals[j] = f2bf(tile[threadIdx.x][threadIdx.y + j * 8]);
  for (int rr = 0; rr < rep; rr++) {
    short* d = dst + (long)(z * rep + rr) * dstZ;
    #pragma unroll
    for (int j = 0; j < 4; j++)
      d[(long)(c0 + threadIdx.y + j * 8) * ldDst + r0 + threadIdx.x] = vals[j];
  }
}

// ---------------- generic bf16 MFMA GEMM (projections + final conv) ----------------
template<int BIAS_MODE, int OUT_F32>   // BIAS_MODE: 0 none, 1 per-row(m), 2 per-col(n)
__global__ __launch_bounds__(256) void k_gemm_bt(
    const short* __restrict__ Ab, long aStr, int aDiv, int aI0, int lda,
    const short* __restrict__ Bb, long bStr, int bDiv, int bI0, int ldb,
    void* __restrict__ Cb, long cStr, int cDiv, int cI0, int ldc,
    const float* __restrict__ bias, int K) {
  __shared__ short As[128 * 32];
  __shared__ short Bs[128 * 32];
  const int z = blockIdx.z;
  const short* A = Ab + (long)((aI0 + z) / aDiv) * aStr;
  const short* B = Bb + (long)((bI0 + z) / bDiv) * bStr;
  const int m0 = blockIdx.y * 128, n0 = blockIdx.x * 128;
  const int t = threadIdx.x;
  const int lane = t & 63, wave = t >> 6;
  const int wr = wave >> 1, wc = wave & 1;

  const int sr = t >> 2;
  const int sc = (t & 3) * 8;
  const short* Ag0 = A + (long)(m0 + sr) * lda + sc;
  const short* Ag1 = A + (long)(m0 + 64 + sr) * lda + sc;
  const short* Bg0 = B + (long)(n0 + sr) * ldb + sc;
  const short* Bg1 = B + (long)(n0 + 64 + sr) * ldb + sc;
  short* lA0 = As + wave * 512;
  short* lA1 = As + 2048 + wave * 512;
  short* lB0 = Bs + wave * 512;
  short* lB1 = Bs + 2048 + wave * 512;

  f32x4 acc[4][4];
  #pragma unroll
  for (int i = 0; i < 4; i++)
    #pragma unroll
    for (int j = 0; j < 4; j++)
      acc[i][j] = (f32x4){0.f, 0.f, 0.f, 0.f};

  const int fr = lane & 15;
  const int fk = (lane >> 4) * 8;

  for (int k0 = 0; k0 < K; k0 += 32) {
    __syncthreads();
    gld16(Ag0 + k0, lA0);
    gld16(Ag1 + k0, lA1);
    gld16(Bg0 + k0, lB0);
    gld16(Bg1 + k0, lB1);
    __syncthreads();
    short8 af[4], bfr[4];
    #pragma unroll
    for (int mf = 0; mf < 4; mf++)
      af[mf] = *(const short8*)&As[(wr * 64 + mf * 16 + fr) * 32 + fk];
    #pragma unroll
    for (int nf = 0; nf < 4; nf++)
      bfr[nf] = *(const short8*)&Bs[(wc * 64 + nf * 16 + fr) * 32 + fk];
    #pragma unroll
    for (int mf = 0; mf < 4; mf++)
      #pragma unroll
      for (int nf = 0; nf < 4; nf++)
        acc[mf][nf] = __builtin_amdgcn_mfma_f32_16x16x32_bf16(af[mf], bfr[nf], acc[mf][nf], 0, 0, 0);
  }

  const int cc = lane & 15;
  const int rg = (lane >> 4) * 4;
  const long coff = (long)((cI0 + z) / cDiv) * cStr;
  #pragma unroll
  for (int mf = 0; mf < 4; mf++) {
    #pragma unroll
    for (int nf = 0; nf < 4; nf++) {
      #pragma unroll
      for (int j = 0; j < 4; j++) {
        int m = m0 + wr * 64 + mf * 16 + rg + j;
        int n = n0 + wc * 64 + nf * 16 + cc;
        float v = acc[mf][nf][j];
        if (BIAS_MODE == 1) v += bias[m];
        if (BIAS_MODE == 2) v += bias[n];
        if (OUT_F32) ((float*)Cb)[coff + (long)m * ldc + n] = v;
        else         ((short*)Cb)[coff + (long)m * ldc + n] = f2bf(v);
      }
    }
  }
}

// ---------------- fused flash cross-attention ----------------
// Block: 128 Q-rows (p) x 256 V-channels (c), 8 waves (512 thr).
// blockIdx.x = pblk (18); blockIdx.y: 0 -> layer1, 1/2 -> layer2 c-half; blockIdx.z = z (16).
// Per KV-tile (128 q): S = Q*K^T (K=256, MFMA, S in regs) -> online softmax (reg stats +
// LDS cross-wave exchange) -> P~ bf16 into LDS -> O += P~*V (MFMA). Epilogue: O/l -> featT.
// LDS: Qp (8x[128][32] persistent, 64KB) | STG (K or V staging, 32KB, stats aliased) |
//      P [128][136] (pad -> 2-way instead of 16-way on A-reads).  Total 130 KB.
__global__ __launch_bounds__(512) void k_flash(
    const short* __restrict__ q1t, const short* __restrict__ k1t, const short* __restrict__ ffb,
    const short* __restrict__ q2t, const short* __restrict__ k2t, const short* __restrict__ mvb,
    short* __restrict__ featT) {
  __shared__ short smem[66560];          // 32768 Qp | 16384 STG | 17408 P
  short* Qp  = smem;                     // [8][128][32]
  short* STG = smem + 32768;             // K: [2][128][32]; V: [2][256][32]
  short* Pl  = smem + 49152;             // [128][136]
  float* ST  = (float*)STG;              // [128][4] stats (aliased; phases disjoint)

  const long QKZ = PPIX * 256;
  const long FEAT_Z = PPIX * FEATC;
  const int y = blockIdx.y, z = blockIdx.z;
  const int t = threadIdx.x;
  const int w = t >> 6, lane = t & 63;
  const int wr = w >> 2, wq = w & 3;          // p-half / (q-quarter | c-quarter)
  const int fr = lane & 15, fkg = lane >> 4;  // frag row, k-group
  const int p0 = blockIdx.x * 128;
  const int sr = t >> 2, sc = (t & 3) * 8;    // staging row / col8

  const short *Q, *K, *V; int col0;
  if (y == 0) {        // layer1: query=memory(q1t per z), ref=flow (k1t, ff per b)
    Q = q1t + (long)z * QKZ;  K = k1t + (long)(z >> 2) * QKZ;
    V = ffb + (long)(z >> 2) * (256 * PPIX);  col0 = 1280;
  } else {             // layer2: query=flow (q2t per b), ref=memory (k2t, mv per z)
    int cb = y - 1;
    Q = q2t + (long)(z >> 2) * QKZ;  K = k2t + (long)z * QKZ;
    V = mvb + (long)z * (512 * PPIX) + (long)cb * (256 * PPIX);  col0 = 512 + cb * 256;
  }
  short* outp = featT + (long)z * FEAT_Z + col0;

  // persistent Q stage: 8 chunks [128][32]
  #pragma unroll
  for (int c = 0; c < 8; ++c)
    gld16(Q + (long)(p0 + sr) * 256 + c * 32 + sc, Qp + c * 4096 + w * 512);

  f32x4 acc_o[4][4];
  float mrun[4][4], lrun[4][4];
  #pragma unroll
  for (int mf = 0; mf < 4; mf++)
    #pragma unroll
    for (int j = 0; j < 4; j++) {
      mrun[mf][j] = -3.0e38f; lrun[mf][j] = 0.f;
      acc_o[mf][j] = (f32x4){0.f, 0.f, 0.f, 0.f};
    }

  for (int tile = 0; tile < 18; ++tile) {
    const int q0 = tile * 128;
    f32x4 acc_s[4][2];
    #pragma unroll
    for (int mf = 0; mf < 4; mf++)
      #pragma unroll
      for (int nq = 0; nq < 2; nq++)
        acc_s[mf][nq] = (f32x4){0.f, 0.f, 0.f, 0.f};

    // ---- S = Q K^T over hidden 256: 4 double-stages ----
    #pragma unroll
    for (int dk = 0; dk < 4; ++dk) {
      __syncthreads();
      const short* Kg = K + (long)(q0 + sr) * 256 + dk * 64 + sc;
      gld16(Kg,      STG + w * 512);
      gld16(Kg + 32, STG + 4096 + w * 512);
      __syncthreads();
      #pragma unroll
      for (int h = 0; h < 2; ++h) {
        short8 af[4], bv[2];
        #pragma unroll
        for (int mf = 0; mf < 4; mf++)
          af[mf] = *(const short8*)&Qp[(dk * 2 + h) * 4096 + (wr * 64 + mf * 16 + fr) * 32 + fkg * 8];
        #pragma unroll
        for (int nq = 0; nq < 2; nq++)
          bv[nq] = *(const short8*)&STG[h * 4096 + (wq * 32 + nq * 16 + fr) * 32 + fkg * 8];
        #pragma unroll
        for (int mf = 0; mf < 4; mf++)
          #pragma unroll
          for (int nq = 0; nq < 2; nq++)
            acc_s[mf][nq] = __builtin_amdgcn_mfma_f32_16x16x32_bf16(af[mf], bv[nq], acc_s[mf][nq], 0, 0, 0);
      }
    }

    // ---- online softmax stats (rows: wr*64 + mf*16 + fkg*4 + j) ----
    float rmax[4][4], al[4][4];
    #pragma unroll
    for (int mf = 0; mf < 4; mf++)
      #pragma unroll
      for (int j = 0; j < 4; j++) {
        float v = fmaxf(acc_s[mf][0][j], acc_s[mf][1][j]);
        v = fmaxf(v, __shfl_xor(v, 1));
        v = fmaxf(v, __shfl_xor(v, 2));
        v = fmaxf(v, __shfl_xor(v, 4));
        v = fmaxf(v, __shfl_xor(v, 8));
        rmax[mf][j] = v;
      }
    __syncthreads();                      // all waves done reading STG (K)
    if (fr == 0) {
      #pragma unroll
      for (int mf = 0; mf < 4; mf++)
        #pragma unroll
        for (int j = 0; j < 4; j++)
          ST[(wr * 64 + mf * 16 + fkg * 4 + j) * 4 + wq] = rmax[mf][j];
    }
    __syncthreads();
    #pragma unroll
    for (int mf = 0; mf < 4; mf++)
      #pragma unroll
      for (int j = 0; j < 4; j++) {
        int row = wr * 64 + mf * 16 + fkg * 4 + j;
        float4 g = *(const float4*)&ST[row * 4];
        float mt = fmaxf(fmaxf(g.x, g.y), fmaxf(g.z, g.w));
        float mnew = fmaxf(mrun[mf][j], mt);
        al[mf][j] = __expf(mrun[mf][j] - mnew);
        mrun[mf][j] = mnew;
        acc_s[mf][0][j] = __expf(acc_s[mf][0][j] - mnew);
        acc_s[mf][1][j] = __expf(acc_s[mf][1][j] - mnew);
      }
    // rescale O
    #pragma unroll
    for (int mf = 0; mf < 4; mf++)
      #pragma unroll
      for (int nc = 0; nc < 4; nc++)
        #pragma unroll
        for (int j = 0; j < 4; j++)
          acc_o[mf][nc][j] *= al[mf][j];
    // l partial sums
    float rsum[4][4];
    #pragma unroll
    for (int mf = 0; mf < 4; mf++)
      #pragma unroll
      for (int j = 0; j < 4; j++) {
        float v = acc_s[mf][0][j] + acc_s[mf][1][j];
        v += __shfl_xor(v, 1);
        v += __shfl_xor(v, 2);
        v += __shfl_xor(v, 4);
        v += __shfl_xor(v, 8);
        rsum[mf][j] = v;
      }
    __syncthreads();                      // max-reads done before sum-writes
    if (fr == 0) {
      #pragma unroll
      for (int mf = 0; mf < 4; mf++)
        #pragma unroll
        for (int j = 0; j < 4; j++)
          ST[(wr * 64 + mf * 16 + fkg * 4 + j) * 4 + wq] = rsum[mf][j];
    }
    __syncthreads();
    #pragma unroll
    for (int mf = 0; mf < 4; mf++)
      #pragma unroll
      for (int j = 0; j < 4; j++) {
        int row = wr * 64 + mf * 16 + fkg * 4 + j;
        float4 g = *(const float4*)&ST[row * 4];
        lrun[mf][j] = al[mf][j] * lrun[mf][j] + (g.x + g.y + g.z + g.w);
      }
    // P~ -> LDS
    #pragma unroll
    for (int mf = 0; mf < 4; mf++)
      #pragma unroll
      for (int nq = 0; nq < 2; nq++)
        #pragma unroll
        for (int j = 0; j < 4; j++)
          Pl[(wr * 64 + mf * 16 + fkg * 4 + j) * 136 + wq * 32 + nq * 16 + fr] =
              f2bf(acc_s[mf][nq][j]);

    // ---- O += P~ * V : 2 double-stages over 128 q ----
    #pragma unroll
    for (int dv = 0; dv < 2; ++dv) {
      __syncthreads();                    // P visible; STG free
      const short* Vg0 = V + (long)sr * PPIX + q0 + dv * 64 + sc;          // c rows 0-127
      const short* Vg1 = V + (long)(128 + sr) * PPIX + q0 + dv * 64 + sc;  // c rows 128-255
      gld16(Vg0,      STG + w * 512);
      gld16(Vg1,      STG + 4096 + w * 512);
      gld16(Vg0 + 32, STG + 8192 + w * 512);
      gld16(Vg1 + 32, STG + 12288 + w * 512);
      __syncthreads();
      #pragma unroll
      for (int h = 0; h < 2; ++h) {
        int kk = dv * 2 + h;
        short8 af[4], bv[4];
        #pragma unroll
        for (int mf = 0; mf < 4; mf++)
          af[mf] = *(const short8*)&Pl[(wr * 64 + mf * 16 + fr) * 136 + kk * 32 + fkg * 8];
        #pragma unroll
        for (int nc = 0; nc < 4; nc++)
          bv[nc] = *(const short8*)&STG[h * 8192 + (wq * 64 + nc * 16 + fr) * 32 + fkg * 8];
        #pragma unroll
        for (int mf = 0; mf < 4; mf++)
          #pragma unroll
          for (int nc = 0; nc < 4; nc++)
            acc_o[mf][nc] = __builtin_amdgcn_mfma_f32_16x16x32_bf16(af[mf], bv[nc], acc_o[mf][nc], 0, 0, 0);
      }
    }
  }

  // ---- epilogue: O / l -> featT[z][p][col0 + c] ----
  #pragma unroll
  for (int mf = 0; mf < 4; mf++)
    #pragma unroll
    for (int j = 0; j < 4; j++) {
      float inv = 1.f / lrun[mf][j];
      int p = p0 + wr * 64 + mf * 16 + fkg * 4 + j;
      #pragma unroll
      for (int nc = 0; nc < 4; nc++) {
        int c = wq * 64 + nc * 16 + fr;
        outp[(long)p * FEATC + c] = f2bf(acc_o[mf][nc][j] * inv);
      }
    }
}

extern "C" void kernel_launch(void* const* d_in, const int* in_sizes, int n_in,
                              void* d_out, int out_size, void* d_ws, size_t ws_size,
                              hipStream_t stream) {
  const float* mv  = (const float*)d_in[0];   // [16][512][2304]
  const float* ff  = (const float*)d_in[1];   // [4][256][2304]
  const float* wq1 = (const float*)d_in[2];   // [256][512]
  const float* bq1 = (const float*)d_in[3];
  const float* wk1 = (const float*)d_in[4];   // [256][256]
  const float* bk1 = (const float*)d_in[5];
  const float* wq2 = (const float*)d_in[6];   // [256][256]
  const float* bq2 = (const float*)d_in[7];
  const float* wk2 = (const float*)d_in[8];   // [256][512]
  const float* bk2 = (const float*)d_in[9];
  const float* wdr = (const float*)d_in[10];  // [512][1536]
  const float* bdr = (const float*)d_in[11];
  float* out = (float*)d_out;                 // [16][512][2304]

  // ---- carve workspace ----
  unsigned char* w = (unsigned char*)d_ws;
  auto carve = [&](size_t bytes) -> short* {
    short* r = (short*)w;
    w += (bytes + 255) & ~(size_t)255;
    return r;
  };
  const long FEAT_Z = PPIX * FEATC;
  const long QKZ = PPIX * 256;
  short* featT = carve(16 * FEAT_Z * 2);       // [16][2304][1536] bf16
  short* mv_bf = carve(16L * 512 * PPIX * 2);  // [16][512][2304]
  short* ff_bf = carve(4L * 256 * PPIX * 2);   // [4][256][2304]
  short* q1t   = carve(16 * QKZ * 2);
  short* k2t   = carve(16 * QKZ * 2);
  short* q2t   = carve(4 * QKZ * 2);
  short* k1t   = carve(4 * QKZ * 2);
  short* wq1b  = carve(256L * 512 * 2);
  short* wk1b  = carve(256L * 256 * 2);
  short* wq2b  = carve(256L * 256 * 2);
  short* wk2b  = carve(256L * 512 * 2);
  short* wdrb  = carve(512L * 1536 * 2);

  // ---- prep: converts ----
  auto conv = [&](const float* s, short* d, long n) {
    long blocks = (n / 4 + 255) / 256;
    if (blocks > 2048) blocks = 2048;
    k_conv_bf16<<<dim3((int)blocks), dim3(256), 0, stream>>>(s, d, n / 4);
  };
  conv(mv, mv_bf, 16L * 512 * PPIX);
  conv(ff, ff_bf, 4L * 256 * PPIX);
  conv(wq1, wq1b, 256L * 512);
  conv(wk1, wk1b, 256L * 256);
  conv(wq2, wq2b, 256L * 256);
  conv(wk2, wk2b, 256L * 512);
  conv(wdr, wdrb, 512L * 1536);

  // ---- prep: transposes into featT (cols 0-511 = mvT, 1024-1279 = ffT) ----
  k_transpose_bf16<<<dim3(72, 16, 16), dim3(32, 8), 0, stream>>>(
      mv, 512L * PPIX, featT, FEAT_Z, (int)PPIX, FEATC, 1);
  k_transpose_bf16<<<dim3(72, 8, 4), dim3(32, 8), 0, stream>>>(
      ff, 256L * PPIX, featT + 1024, FEAT_Z, (int)PPIX, FEATC, 4);

  // ---- generic GEMM launcher ----
  auto gemm = [&](int biasMode, int outF32,
                  const short* A, long aStr, int aDiv, int aI0, int lda,
                  const short* B, long bStr, int bDiv, int bI0, int ldb,
                  void* C, long cStr, int cDiv, int cI0, int ldc,
                  const float* bias, int M, int N, int K, int Z) {
    dim3 g(N / 128, M / 128, Z), b(256);
    if (biasMode == 2 && !outF32)
      k_gemm_bt<2, 0><<<g, b, 0, stream>>>(A, aStr, aDiv, aI0, lda, B, bStr, bDiv, bI0, ldb,
                                           C, cStr, cDiv, cI0, ldc, bias, K);
    else if (biasMode == 0 && outF32)
      k_gemm_bt<0, 1><<<g, b, 0, stream>>>(A, aStr, aDiv, aI0, lda, B, bStr, bDiv, bI0, ldb,
                                           C, cStr, cDiv, cI0, ldc, bias, K);
    else if (biasMode == 0 && !outF32)
      k_gemm_bt<0, 0><<<g, b, 0, stream>>>(A, aStr, aDiv, aI0, lda, B, bStr, bDiv, bI0, ldb,
                                           C, cStr, cDiv, cI0, ldc, bias, K);
    else
      k_gemm_bt<1, 1><<<g, b, 0, stream>>>(A, aStr, aDiv, aI0, lda, B, bStr, bDiv, bI0, ldb,
                                           C, cStr, cDiv, cI0, ldc, bias, K);
  };

  // ---- projections (Q/K with bias, bf16 out) ----
  gemm(2, 0, featT, FEAT_Z, 1, 0, FEATC,  wq1b, 0, 1, 0, 512,
       q1t, QKZ, 1, 0, 256,  bq1, (int)PPIX, 256, 512, 16);
  gemm(2, 0, featT, FEAT_Z, 1, 0, FEATC,  wk2b, 0, 1, 0, 512,
       k2t, QKZ, 1, 0, 256,  bk2, (int)PPIX, 256, 512, 16);
  gemm(2, 0, featT + 1024, 4 * FEAT_Z, 1, 0, FEATC,  wq2b, 0, 1, 0, 256,
       q2t, QKZ, 1, 0, 256,  bq2, (int)PPIX, 256, 256, 4);
  gemm(2, 0, featT + 1024, 4 * FEAT_Z, 1, 0, FEATC,  wk1b, 0, 1, 0, 256,
       k1t, QKZ, 1, 0, 256,  bk1, (int)PPIX, 256, 256, 4);

  // ---- fused flash attention: both layers, one dispatch ----
  // y=0: layer1 -> featT cols 1280-1535; y=1,2: layer2 c-halves -> cols 512-1023
  k_flash<<<dim3(18, 3, 16), dim3(512), 0, stream>>>(
      q1t, k1t, ff_bf, q2t, k2t, mv_bf, featT);

  // ---- final 1x1 conv: out[i][o][p] = sum_ch wdr[o][ch]*featT[i][p][ch] + bdr[o] ----
  gemm(1, 1, wdrb, 0, 1, 0, FEATC,  featT, FEAT_Z, 1, 0, FEATC,
       out, 512L * PPIX, 1, 0, (int)PPIX,  bdr, 512, (int)PPIX, FEATC, 16);

  (void)in_sizes; (void)n_in; (void)out_size; (void)ws_size;
}